// Round 2
// baseline (943.211 us; speedup 1.0000x reference)
//
#include <hip/hip_runtime.h>
#include <math.h>

// Problem dims (fixed by setup_inputs): x[B=8][F=256][H=64][T=512] fp32
// states: s_t = A s_{t-1} + Bvec (S=32), states[t] = u_{t+1} where u_t = P_t B
// ycT[f][t] = (states @ Cmat)[t][f]
// out = LN_F( x + gelu(ycT[f][t] + x*D[f]) )

#define SD 32
#define FD 256
#define HD 64
#define TD 512
#define BD 8

// ---------------- Kernel 1: state trajectory via affine doubling ----------------
// u_1 = B; level len: u_{len+m} = A^len u_m + u_len (m=1..len); A^{2len} = (A^len)^2
__global__ __launch_bounds__(256) void k_states(const float* __restrict__ A,
                                                const float* __restrict__ Bvec,
                                                float* __restrict__ states) {
  __shared__ float U[512][32];       // U[t-1][i] = u_t[i]
  __shared__ float P[2][32][33];     // padded: conflict-free row & column reads
  int tid = threadIdx.x;
  for (int idx = tid; idx < 1024; idx += 256)
    P[0][idx >> 5][idx & 31] = A[idx];
  if (tid < 32) U[0][tid] = Bvec[tid];
  __syncthreads();

  int pb = 0;
  const int i = tid & 31;
  for (int len = 1; len < 512; len <<= 1) {
    // preload my P row (conflict-free thanks to 33-pad)
    float pr[32];
#pragma unroll
    for (int k = 0; k < 32; ++k) pr[k] = P[pb][i][k];

    // U[len + j][i] = sum_k P[i][k] * U[j][k] + U[len-1][i]
    for (int idx = tid; idx < len * 32; idx += 256) {
      int j = idx >> 5;  // idx&31 == i (stride 256 is multiple of 32)
      float acc = U[len - 1][i];
      const float4* Uj = (const float4*)(&U[j][0]);
#pragma unroll
      for (int k4 = 0; k4 < 8; ++k4) {
        float4 uv = Uj[k4];                       // broadcast reads
        acc = fmaf(pr[4 * k4 + 0], uv.x, acc);
        acc = fmaf(pr[4 * k4 + 1], uv.y, acc);
        acc = fmaf(pr[4 * k4 + 2], uv.z, acc);
        acc = fmaf(pr[4 * k4 + 3], uv.w, acc);
      }
      U[len + j][i] = acc;
    }

    // P^2 into the other buffer (not needed after len=256)
    if (len < 256) {
      for (int idx = tid; idx < 1024; idx += 256) {
        int ii = idx >> 5, jj = idx & 31;
        float acc = 0.f;
#pragma unroll
        for (int k = 0; k < 32; ++k)
          acc = fmaf(P[pb][ii][k], P[pb][k][jj], acc);
        P[pb ^ 1][ii][jj] = acc;
      }
    }
    __syncthreads();
    if (len < 256) pb ^= 1;
  }

  for (int idx = tid; idx < 512 * 32; idx += 256)
    states[idx] = U[idx >> 5][idx & 31];
}

// ---------------- Kernel 2: ycT[f][t] = sum_s states[t][s] * Cmat[s][f] ----------------
__global__ __launch_bounds__(256) void k_yc(const float* __restrict__ states,
                                            const float* __restrict__ Cmat,
                                            float* __restrict__ ycT) {
  int t = blockIdx.x;       // 512
  int f = threadIdx.x;      // 256
  const float* st = states + t * SD;   // uniform address -> scalar/broadcast loads
  float acc = 0.f;
#pragma unroll
  for (int s = 0; s < SD; ++s)
    acc = fmaf(st[s], Cmat[s * FD + f], acc);   // Cmat read coalesced over f
  ycT[f * TD + t] = acc;    // scattered 4B stores; merged in L2 (512 KB total)
}

// ---------------- Kernel 3: fused gelu + residual + LayerNorm over F ----------------
__device__ __forceinline__ float gelu_exact(float v) {
  return 0.5f * v * (1.0f + erff(v * 0.70710678118654752440f));
}

__global__ __launch_bounds__(256) void k_main(const float* __restrict__ x,
                                              const float* __restrict__ ycT,
                                              const float* __restrict__ D,
                                              const float* __restrict__ lnw,
                                              const float* __restrict__ lnb,
                                              float* __restrict__ out) {
  int bid = blockIdx.x;          // 4096 = B*H*(T/64)
  int tc = bid & 7;              // t-chunk
  int bh = bid >> 3;             // b*64 + h
  int b = bh >> 6, h = bh & 63;
  int tIdx = threadIdx.x & 63;   // lane -> t (coalesced)
  int fs = threadIdx.x >> 6;     // wave -> f quarter
  int t = (tc << 6) + tIdx;

  const size_t fstride = (size_t)HD * TD;                    // 32768
  size_t base = (size_t)b * (FD * fstride) + (size_t)h * TD + (size_t)t;
  int f0 = fs << 6;

  float vals[64];
  float sum = 0.f, ssq = 0.f;
  size_t xoff = base + (size_t)f0 * fstride;
  int ycoff = f0 * TD + t;
#pragma unroll
  for (int k = 0; k < 64; ++k) {
    float xv = x[xoff];              // 64 consecutive t per wave: coalesced
    float yv = ycT[ycoff];           // coalesced + L2-resident
    float dv = D[f0 + k];            // wave-uniform -> scalar load
    float pre = fmaf(xv, dv, yv);
    float v = xv + gelu_exact(pre);
    vals[k] = v;
    sum += v;
    ssq = fmaf(v, v, ssq);
    xoff += fstride;
    ycoff += TD;
  }

  __shared__ float red[2][4][64];
  red[0][fs][tIdx] = sum;
  red[1][fs][tIdx] = ssq;
  __syncthreads();
  float S  = red[0][0][tIdx] + red[0][1][tIdx] + red[0][2][tIdx] + red[0][3][tIdx];
  float SS = red[1][0][tIdx] + red[1][1][tIdx] + red[1][2][tIdx] + red[1][3][tIdx];
  float mu = S * (1.0f / 256.0f);
  float var = fmaf(SS, 1.0f / 256.0f, -mu * mu);
  float rstd = rsqrtf(var + 1e-5f);

  size_t ooff = base + (size_t)f0 * fstride;
#pragma unroll
  for (int k = 0; k < 64; ++k) {
    int f = f0 + k;
    float o = fmaf((vals[k] - mu) * rstd, lnw[f], lnb[f]);
    out[ooff] = o;                   // coalesced
    ooff += fstride;
  }
}

extern "C" void kernel_launch(void* const* d_in, const int* in_sizes, int n_in,
                              void* d_out, int out_size, void* d_ws, size_t ws_size,
                              hipStream_t stream) {
  const float* x    = (const float*)d_in[0];
  const float* A    = (const float*)d_in[1];
  const float* Bvec = (const float*)d_in[2];
  const float* Cmat = (const float*)d_in[3];
  const float* D    = (const float*)d_in[4];
  const float* lnw  = (const float*)d_in[5];
  const float* lnb  = (const float*)d_in[6];
  float* out = (float*)d_out;

  float* states = (float*)d_ws;            // 512*32 floats = 64 KB
  float* ycT    = states + TD * SD;        // 256*512 floats = 512 KB

  k_states<<<1, 256, 0, stream>>>(A, Bvec, states);
  k_yc<<<TD, 256, 0, stream>>>(states, Cmat, ycT);
  k_main<<<BD * HD * (TD / 64), 256, 0, stream>>>(x, ycT, D, lnw, lnb, out);
}

// Round 3
// 488.954 us; speedup vs baseline: 1.9290x; 1.9290x over previous
//
#include <hip/hip_runtime.h>
#include <math.h>

// x[B=8][F=256][H=64][T=512] fp32; s_t = A s_{t-1} + Bvec (S=32)
// ycT[f][t] = (states @ Cmat)[t][f]
// out = LN_F( x + gelu(ycT[f][t] + x*D[f]) )

#define SD 32
#define FD 256
#define HD 64
#define TD 512
#define BD 8

// ---------------- Kernel 1: state trajectory via affine doubling ----------------
__global__ __launch_bounds__(256) void k_states(const float* __restrict__ A,
                                                const float* __restrict__ Bvec,
                                                float* __restrict__ states) {
  __shared__ float U[512][32];
  __shared__ float P[2][32][33];
  int tid = threadIdx.x;
  for (int idx = tid; idx < 1024; idx += 256)
    P[0][idx >> 5][idx & 31] = A[idx];
  if (tid < 32) U[0][tid] = Bvec[tid];
  __syncthreads();

  int pb = 0;
  const int i = tid & 31;
  for (int len = 1; len < 512; len <<= 1) {
    float pr[32];
#pragma unroll
    for (int k = 0; k < 32; ++k) pr[k] = P[pb][i][k];

    for (int idx = tid; idx < len * 32; idx += 256) {
      int j = idx >> 5;
      float acc = U[len - 1][i];
      const float4* Uj = (const float4*)(&U[j][0]);
#pragma unroll
      for (int k4 = 0; k4 < 8; ++k4) {
        float4 uv = Uj[k4];
        acc = fmaf(pr[4 * k4 + 0], uv.x, acc);
        acc = fmaf(pr[4 * k4 + 1], uv.y, acc);
        acc = fmaf(pr[4 * k4 + 2], uv.z, acc);
        acc = fmaf(pr[4 * k4 + 3], uv.w, acc);
      }
      U[len + j][i] = acc;
    }

    if (len < 256) {
      for (int idx = tid; idx < 1024; idx += 256) {
        int ii = idx >> 5, jj = idx & 31;
        float acc = 0.f;
#pragma unroll
        for (int k = 0; k < 32; ++k)
          acc = fmaf(P[pb][ii][k], P[pb][k][jj], acc);
        P[pb ^ 1][ii][jj] = acc;
      }
    }
    __syncthreads();
    if (len < 256) pb ^= 1;
  }

  for (int idx = tid; idx < 512 * 32; idx += 256)
    states[idx] = U[idx >> 5][idx & 31];
}

// ---------------- Kernel 2: ycT[f][t], f-major (coalesced stores) ----------------
__global__ __launch_bounds__(512) void k_yc(const float* __restrict__ states,
                                            const float* __restrict__ Cmat,
                                            float* __restrict__ ycT) {
  int f = blockIdx.x;       // 256 (block-uniform -> Cmat via scalar loads)
  int t = threadIdx.x;      // 512
  const float4* st = (const float4*)(states + t * SD);  // lane-local row, L2/L3-resident
  float acc = 0.f;
#pragma unroll
  for (int s4 = 0; s4 < 8; ++s4) {
    float4 sv = st[s4];
    acc = fmaf(sv.x, Cmat[(s4 * 4 + 0) * FD + f], acc);
    acc = fmaf(sv.y, Cmat[(s4 * 4 + 1) * FD + f], acc);
    acc = fmaf(sv.z, Cmat[(s4 * 4 + 2) * FD + f], acc);
    acc = fmaf(sv.w, Cmat[(s4 * 4 + 3) * FD + f], acc);
  }
  ycT[f * TD + t] = acc;    // coalesced 2KB/block
}

// ---------------- Kernel 3: fused gelu + residual + LayerNorm over F ----------------
__device__ __forceinline__ float gelu_exact(float v) {
  return 0.5f * v * (1.0f + erff(v * 0.70710678118654752440f));
}

__global__ __launch_bounds__(1024, 8) void k_main(const float* __restrict__ x,
                                                  const float* __restrict__ ycT,
                                                  const float* __restrict__ D,
                                                  const float* __restrict__ lnw,
                                                  const float* __restrict__ lnb,
                                                  float* __restrict__ out) {
  __shared__ float tile[FD * 64];   // 64 KB; rows f=0..255, cols t=0..63; reused for red
  int bid = blockIdx.x;             // 4096 = B*H*(T/64)
  int tc = bid & 7;
  int bh = bid >> 3;
  int b = bh >> 6, h = bh & 63;
  int tid = threadIdx.x;

  const size_t fstride = (size_t)HD * TD;  // 32768
  size_t bhbase = (size_t)b * (FD * fstride) + (size_t)h * TD + (size_t)(tc << 6);
  int tbase = (tc << 6);

  // Phase 1: float4 loads, fused D-scale + GELU + residual, store v to LDS
#pragma unroll
  for (int i = 0; i < 4; ++i) {
    int gidx = i * 1024 + tid;       // 4096 float4 slots = 256 f x 16 quads
    int f = gidx >> 4;
    int tq = (gidx & 15) << 2;       // t offset within 64
    float4 xv = *(const float4*)(x + bhbase + (size_t)f * fstride + tq);
    float4 yv = *(const float4*)(ycT + f * TD + tbase + tq);
    float dv = D[f];
    float4 v;
    v.x = xv.x + gelu_exact(fmaf(xv.x, dv, yv.x));
    v.y = xv.y + gelu_exact(fmaf(xv.y, dv, yv.y));
    v.z = xv.z + gelu_exact(fmaf(xv.z, dv, yv.z));
    v.w = xv.w + gelu_exact(fmaf(xv.w, dv, yv.w));
    *(float4*)(tile + f * 64 + tq) = v;
  }
  __syncthreads();

  // Phase 2: thread (w,lane) owns f=w*16..+15 at t=lane; pull vals, partial stats
  int lane = tid & 63, w = tid >> 6;
  float vals[16];
  float sum = 0.f, ssq = 0.f;
#pragma unroll
  for (int k = 0; k < 16; ++k) {
    float v = tile[(w * 16 + k) * 64 + lane];  // banks: lane%32, 2-way = free
    vals[k] = v;
    sum += v;
    ssq = fmaf(v, v, ssq);
  }
  __syncthreads();                  // all tile reads done before red overwrite
  tile[tid] = sum;                  // red0[w][lane]
  tile[1024 + tid] = ssq;           // red1[w][lane]
  __syncthreads();
  float S = 0.f, SS = 0.f;
#pragma unroll
  for (int w2 = 0; w2 < 16; ++w2) {
    S += tile[w2 * 64 + lane];
    SS += tile[1024 + w2 * 64 + lane];
  }
  float mu = S * (1.0f / 256.0f);
  float var = fmaf(SS, 1.0f / 256.0f, -mu * mu);
  float rstd = rsqrtf(var + 1e-5f);

  // Phase 3: LN + coalesced stores (256B per wave per f)
  size_t obase = bhbase + (size_t)lane;
#pragma unroll
  for (int k = 0; k < 16; ++k) {
    int f = w * 16 + k;              // wave-uniform -> lnw/lnb scalar loads
    out[obase + (size_t)f * fstride] = fmaf((vals[k] - mu) * rstd, lnw[f], lnb[f]);
  }
}

extern "C" void kernel_launch(void* const* d_in, const int* in_sizes, int n_in,
                              void* d_out, int out_size, void* d_ws, size_t ws_size,
                              hipStream_t stream) {
  const float* x    = (const float*)d_in[0];
  const float* A    = (const float*)d_in[1];
  const float* Bvec = (const float*)d_in[2];
  const float* Cmat = (const float*)d_in[3];
  const float* D    = (const float*)d_in[4];
  const float* lnw  = (const float*)d_in[5];
  const float* lnb  = (const float*)d_in[6];
  float* out = (float*)d_out;

  float* states = (float*)d_ws;            // 512*32 floats = 64 KB
  float* ycT    = states + TD * SD;        // 256*512 floats = 512 KB

  k_states<<<1, 256, 0, stream>>>(A, Bvec, states);
  k_yc<<<FD, 512, 0, stream>>>(states, Cmat, ycT);
  k_main<<<BD * HD * (TD / 64), 1024, 0, stream>>>(x, ycT, D, lnw, lnb, out);
}

// Round 4
// 487.885 us; speedup vs baseline: 1.9333x; 1.0022x over previous
//
#include <hip/hip_runtime.h>
#include <math.h>

// x[B=8][F=256][H=64][T=512] fp32; s_t = A s_{t-1} + Bvec (S=32)
// ycT[f][t] = (states @ Cmat)[t][f]
// out = LN_F( x + gelu(ycT[f][t] + x*D[f]) )

#define SD 32
#define FD 256
#define HD 64
#define TD 512
#define BD 8

// ---------------- Kernel 1: state trajectory via affine doubling ----------------
__global__ __launch_bounds__(256) void k_states(const float* __restrict__ A,
                                                const float* __restrict__ Bvec,
                                                float* __restrict__ states) {
  __shared__ float U[512][32];
  __shared__ float P[2][32][33];
  int tid = threadIdx.x;
  for (int idx = tid; idx < 1024; idx += 256)
    P[0][idx >> 5][idx & 31] = A[idx];
  if (tid < 32) U[0][tid] = Bvec[tid];
  __syncthreads();

  int pb = 0;
  const int i = tid & 31;
  for (int len = 1; len < 512; len <<= 1) {
    float pr[32];
#pragma unroll
    for (int k = 0; k < 32; ++k) pr[k] = P[pb][i][k];

    for (int idx = tid; idx < len * 32; idx += 256) {
      int j = idx >> 5;
      float acc = U[len - 1][i];
      const float4* Uj = (const float4*)(&U[j][0]);
#pragma unroll
      for (int k4 = 0; k4 < 8; ++k4) {
        float4 uv = Uj[k4];
        acc = fmaf(pr[4 * k4 + 0], uv.x, acc);
        acc = fmaf(pr[4 * k4 + 1], uv.y, acc);
        acc = fmaf(pr[4 * k4 + 2], uv.z, acc);
        acc = fmaf(pr[4 * k4 + 3], uv.w, acc);
      }
      U[len + j][i] = acc;
    }

    if (len < 256) {
      for (int idx = tid; idx < 1024; idx += 256) {
        int ii = idx >> 5, jj = idx & 31;
        float acc = 0.f;
#pragma unroll
        for (int k = 0; k < 32; ++k)
          acc = fmaf(P[pb][ii][k], P[pb][k][jj], acc);
        P[pb ^ 1][ii][jj] = acc;
      }
    }
    __syncthreads();
    if (len < 256) pb ^= 1;
  }

  for (int idx = tid; idx < 512 * 32; idx += 256)
    states[idx] = U[idx >> 5][idx & 31];
}

// ---------------- Kernel 2: ycT[f][t], f-major (coalesced stores) ----------------
__global__ __launch_bounds__(512) void k_yc(const float* __restrict__ states,
                                            const float* __restrict__ Cmat,
                                            float* __restrict__ ycT) {
  int f = blockIdx.x;       // 256 (block-uniform -> Cmat via scalar loads)
  int t = threadIdx.x;      // 512
  const float4* st = (const float4*)(states + t * SD);  // lane-local row, L2-resident
  float acc = 0.f;
#pragma unroll
  for (int s4 = 0; s4 < 8; ++s4) {
    float4 sv = st[s4];
    acc = fmaf(sv.x, Cmat[(s4 * 4 + 0) * FD + f], acc);
    acc = fmaf(sv.y, Cmat[(s4 * 4 + 1) * FD + f], acc);
    acc = fmaf(sv.z, Cmat[(s4 * 4 + 2) * FD + f], acc);
    acc = fmaf(sv.w, Cmat[(s4 * 4 + 3) * FD + f], acc);
  }
  ycT[f * TD + t] = acc;    // coalesced 2KB/block
}

// ---------------- Kernel 3: fused gelu + residual + LayerNorm over F ----------------
__device__ __forceinline__ float gelu_exact(float v) {
  return 0.5f * v * (1.0f + erff(v * 0.70710678118654752440f));
}

__global__ __launch_bounds__(1024, 8) void k_main(const float* __restrict__ x,
                                                  const float* __restrict__ ycT,
                                                  const float* __restrict__ D,
                                                  const float* __restrict__ lnw,
                                                  const float* __restrict__ lnb,
                                                  float* __restrict__ out) {
  __shared__ float tile[FD * 64];      // 64 KB: rows f, cols t (stays valid to the end)
  __shared__ float red0[16][64];       // 4 KB
  __shared__ float red1[16][64];       // 4 KB
  __shared__ float mured[64];
  __shared__ float rstdred[64];
  int bid = blockIdx.x;                // 4096 = B*H*(T/64)
  int tc = bid & 7;
  int bh = bid >> 3;
  int b = bh >> 6, h = bh & 63;
  int tid = threadIdx.x;

  const size_t fstride = (size_t)HD * TD;  // 32768
  size_t bhbase = (size_t)b * (FD * fstride) + (size_t)h * TD + (size_t)(tc << 6);
  int tbase = tc << 6;

  // Phase 0: issue all 8 global float4 loads back-to-back (max MLP)
  float4 xq[4], yq[4];
#pragma unroll
  for (int i = 0; i < 4; ++i) {
    int gidx = i * 1024 + tid;         // f = gidx>>4, tq = (gidx&15)*4
    int f = gidx >> 4;
    int tq = (gidx & 15) << 2;
    xq[i] = *(const float4*)(x + bhbase + (size_t)f * fstride + tq);
    yq[i] = *(const float4*)(ycT + f * TD + tbase + tq);
  }

  // Phase 1: fused D-scale + exact GELU + residual -> LDS tile
#pragma unroll
  for (int i = 0; i < 4; ++i) {
    int gidx = i * 1024 + tid;
    int f = gidx >> 4;
    int tq = (gidx & 15) << 2;
    float dv = D[f];
    float4 v;
    v.x = xq[i].x + gelu_exact(fmaf(xq[i].x, dv, yq[i].x));
    v.y = xq[i].y + gelu_exact(fmaf(xq[i].y, dv, yq[i].y));
    v.z = xq[i].z + gelu_exact(fmaf(xq[i].z, dv, yq[i].z));
    v.w = xq[i].w + gelu_exact(fmaf(xq[i].w, dv, yq[i].w));
    *(float4*)(tile + f * 64 + tq) = v;
  }
  __syncthreads();

  // Phase 2: wave w owns f=w*16..+15 at t=lane; stats over F via LDS
  int lane = tid & 63, w = tid >> 6;
  float sum = 0.f, ssq = 0.f;
#pragma unroll
  for (int k = 0; k < 16; ++k) {
    float v = tile[(w * 16 + k) * 64 + lane];  // stride-1 across lanes: 2-way = free
    sum += v;
    ssq = fmaf(v, v, ssq);
  }
  red0[w][lane] = sum;
  red1[w][lane] = ssq;
  __syncthreads();
  float S = 0.f, SS = 0.f;
#pragma unroll
  for (int w2 = 0; w2 < 16; ++w2) {
    S += red0[w2][lane];
    SS += red1[w2][lane];
  }
  float mu = S * (1.0f / 256.0f);
  float var = fmaf(SS, 1.0f / 256.0f, -mu * mu);
  float rstd = rsqrtf(var + 1e-5f);
  if (w == 0) {
    mured[lane] = mu;
    rstdred[lane] = rstd;
  }
  __syncthreads();

  // Phase 3: LN + float4 stores (tile untouched since phase 1)
#pragma unroll
  for (int i = 0; i < 4; ++i) {
    int gidx = i * 1024 + tid;
    int f = gidx >> 4;
    int tq = (gidx & 15) << 2;
    float4 v = *(const float4*)(tile + f * 64 + tq);
    float4 m4 = *(const float4*)(mured + tq);     // broadcast across f-groups: free
    float4 r4 = *(const float4*)(rstdred + tq);
    float lw = lnw[f], lb = lnb[f];
    float4 o;
    o.x = fmaf((v.x - m4.x) * r4.x, lw, lb);
    o.y = fmaf((v.y - m4.y) * r4.y, lw, lb);
    o.z = fmaf((v.z - m4.z) * r4.z, lw, lb);
    o.w = fmaf((v.w - m4.w) * r4.w, lw, lb);
    *(float4*)(out + bhbase + (size_t)f * fstride + tq) = o;
  }
}

extern "C" void kernel_launch(void* const* d_in, const int* in_sizes, int n_in,
                              void* d_out, int out_size, void* d_ws, size_t ws_size,
                              hipStream_t stream) {
  const float* x    = (const float*)d_in[0];
  const float* A    = (const float*)d_in[1];
  const float* Bvec = (const float*)d_in[2];
  const float* Cmat = (const float*)d_in[3];
  const float* D    = (const float*)d_in[4];
  const float* lnw  = (const float*)d_in[5];
  const float* lnb  = (const float*)d_in[6];
  float* out = (float*)d_out;

  float* states = (float*)d_ws;            // 512*32 floats = 64 KB
  float* ycT    = states + TD * SD;        // 256*512 floats = 512 KB

  k_states<<<1, 256, 0, stream>>>(A, Bvec, states);
  k_yc<<<FD, 512, 0, stream>>>(states, Cmat, ycT);
  k_main<<<BD * HD * (TD / 64), 1024, 0, stream>>>(x, ycT, D, lnw, lnb, out);
}